// Round 10
// baseline (546.829 us; speedup 1.0000x reference)
//
#include <hip/hip_runtime.h>
#include <stdint.h>

#define NUM_HEADS 12
#define HEAD_DIM  64
#define HWDIM     56
#define PHDIM     28
#define NTOK      785     // 28*28+1
#define NIN       3137    // 56*56+1
#define BATCH     16
#define DMODEL    768
#define BHCNT     192     // BATCH*NUM_HEADS
#define LOG2E     1.44269504f

typedef __attribute__((ext_vector_type(8))) short bf16x8;
typedef __attribute__((ext_vector_type(4))) short s16x4;
typedef __attribute__((ext_vector_type(4))) float f32x4;

static __device__ __forceinline__ float bf2f(short s) {
  unsigned u = ((unsigned)(unsigned short)s) << 16;
  float f; __builtin_memcpy(&f, &u, 4); return f;
}
static __device__ __forceinline__ short f2bf(float f) {
  unsigned u; __builtin_memcpy(&u, &f, 4);
  unsigned r = u + 0x7FFFu + ((u >> 16) & 1u);
  return (short)(r >> 16);
}
static __device__ __forceinline__ float fexp2(float x) {
#if defined(__has_builtin)
#if __has_builtin(__builtin_amdgcn_exp2f)
  return __builtin_amdgcn_exp2f(x);
#else
  return exp2f(x);
#endif
#else
  return exp2f(x);
#endif
}

// bijective XCD chunking (m204)
static __device__ __forceinline__ int xcd_chunk(int orig, int nwg) {
  int xcd = orig & 7;
  int within = orig >> 3;
  int q = nwg >> 3, r = nwg & 7;
  int base = (xcd < r) ? xcd * (q + 1) : r * (q + 1) + (xcd - r) * q;
  return base + within;
}

#if defined(__has_builtin)
#if __has_builtin(__builtin_amdgcn_global_load_lds)
#define HAVE_GLLDS 1
#endif
#endif

static __device__ __forceinline__ void gl_lds16(const short* g, short* l) {
#ifdef HAVE_GLLDS
  __builtin_amdgcn_global_load_lds(
      (const __attribute__((address_space(1))) void*)g,
      (__attribute__((address_space(3))) void*)l, 16, 0, 0);
#else
  int lane = threadIdx.x & 63;
  *(bf16x8*)(l + lane * 8) = *(const bf16x8*)g;
#endif
}

// ---------------------------------------------------------------- pool + LN
__global__ __launch_bounds__(192) void pool_ln_kernel(
    const float* __restrict__ x,
    const float* __restrict__ wq9, const float* __restrict__ wk9, const float* __restrict__ wv9,
    const float* __restrict__ gq, const float* __restrict__ bq,
    const float* __restrict__ gk, const float* __restrict__ bk,
    const float* __restrict__ gv, const float* __restrict__ bv,
    short* __restrict__ Pq, short* __restrict__ Pk, short* __restrict__ Pv)
{
  __shared__ __align__(16) float wt_s[3][9][64];   // [conv][tap][c]
  int tid = threadIdx.x;
  int blk = blockIdx.x;
  int b = blk / 197;
  int n0 = (blk - b * 197) * 4;

  for (int idx = tid; idx < 3 * 576; idx += 192) {
    int conv = idx / 576, rem = idx - conv * 576;
    int c = rem / 9, tap = rem - c * 9;
    const float* wsrc = (conv == 0) ? wq9 : (conv == 1) ? wk9 : wv9;
    wt_s[conv][tap][c] = wsrc[c * 9 + tap];
  }
  __syncthreads();

  int ch0 = tid * 4;
  int c4 = ch0 & 63;
  f32x4 g_q = *(const f32x4*)&gq[c4], b_q = *(const f32x4*)&bq[c4];
  f32x4 g_k = *(const f32x4*)&gk[c4], b_k = *(const f32x4*)&bk[c4];
  f32x4 g_v = *(const f32x4*)&gv[c4], b_v = *(const f32x4*)&bv[c4];

  for (int tt = 0; tt < 4; ++tt) {
    int n = n0 + tt;
    if (n >= NTOK) break;
    f32x4 aq = (f32x4){0.f, 0.f, 0.f, 0.f}, ak = aq, av = aq;
    if (n == 0) {
      f32x4 x4 = *(const f32x4*)&x[((size_t)b * NIN) * DMODEL + ch0];
      aq = ak = av = x4;
    } else {
      int s = n - 1;
      int i = s / PHDIM, j = s - i * PHDIM;
#pragma unroll
      for (int di = 0; di < 3; ++di) {
        int ii = 2 * i - 1 + di;
        if (ii < 0 || ii >= HWDIM) continue;
#pragma unroll
        for (int dj = 0; dj < 3; ++dj) {
          int jj = 2 * j - 1 + dj;
          if (jj < 0 || jj >= HWDIM) continue;
          f32x4 x4 = *(const f32x4*)&x[((size_t)b * NIN + 1 + ii * HWDIM + jj) * DMODEL + ch0];
          int tap = di * 3 + dj;
          f32x4 w0 = *(const f32x4*)&wt_s[0][tap][c4];
          f32x4 w1 = *(const f32x4*)&wt_s[1][tap][c4];
          f32x4 w2 = *(const f32x4*)&wt_s[2][tap][c4];
          aq += w0 * x4; ak += w1 * x4; av += w2 * x4;
        }
      }
    }
    size_t obase = ((size_t)b * NTOK + n) * DMODEL + ch0;
    {
      float sm = aq[0] + aq[1] + aq[2] + aq[3];
#pragma unroll
      for (int m = 1; m < 16; m <<= 1) sm += __shfl_xor(sm, m);
      float mn = sm * (1.f / 64.f);
      f32x4 d = aq - mn;
      float vs = d[0]*d[0] + d[1]*d[1] + d[2]*d[2] + d[3]*d[3];
#pragma unroll
      for (int m = 1; m < 16; m <<= 1) vs += __shfl_xor(vs, m);
      float rs = rsqrtf(vs * (1.f / 64.f) + 1e-5f);
      s16x4 o;
#pragma unroll
      for (int e = 0; e < 4; ++e) o[e] = f2bf(d[e] * rs * g_q[e] + b_q[e]);
      *(s16x4*)&Pq[obase] = o;
    }
    {
      float sm = ak[0] + ak[1] + ak[2] + ak[3];
#pragma unroll
      for (int m = 1; m < 16; m <<= 1) sm += __shfl_xor(sm, m);
      float mn = sm * (1.f / 64.f);
      f32x4 d = ak - mn;
      float vs = d[0]*d[0] + d[1]*d[1] + d[2]*d[2] + d[3]*d[3];
#pragma unroll
      for (int m = 1; m < 16; m <<= 1) vs += __shfl_xor(vs, m);
      float rs = rsqrtf(vs * (1.f / 64.f) + 1e-5f);
      s16x4 o;
#pragma unroll
      for (int e = 0; e < 4; ++e) o[e] = f2bf(d[e] * rs * g_k[e] + b_k[e]);
      *(s16x4*)&Pk[obase] = o;
    }
    {
      float sm = av[0] + av[1] + av[2] + av[3];
#pragma unroll
      for (int m = 1; m < 16; m <<= 1) sm += __shfl_xor(sm, m);
      float mn = sm * (1.f / 64.f);
      f32x4 d = av - mn;
      float vs = d[0]*d[0] + d[1]*d[1] + d[2]*d[2] + d[3]*d[3];
#pragma unroll
      for (int m = 1; m < 16; m <<= 1) vs += __shfl_xor(vs, m);
      float rs = rsqrtf(vs * (1.f / 64.f) + 1e-5f);
      s16x4 o;
#pragma unroll
      for (int e = 0; e < 4; ++e) o[e] = f2bf(d[e] * rs * g_v[e] + b_v[e]);
      *(s16x4*)&Pv[obase] = o;
    }
  }
}

// ------------------------------------------------- weight transpose fp32->bf16
__global__ __launch_bounds__(256) void trans_kernel(
    const float* __restrict__ s0, const float* __restrict__ s1,
    const float* __restrict__ s2, const float* __restrict__ s3,
    short* __restrict__ d0, short* __restrict__ d1,
    short* __restrict__ d2, short* __restrict__ d3)
{
  __shared__ float tile[32][33];
  int z = blockIdx.z;
  const float* s = (z == 0) ? s0 : (z == 1) ? s1 : (z == 2) ? s2 : s3;
  short* d = (z == 0) ? d0 : (z == 1) ? d1 : (z == 2) ? d2 : d3;
  int k0 = blockIdx.x * 32, n0 = blockIdx.y * 32;
  int tx = threadIdx.x, ty = threadIdx.y;   // 32 x 8
#pragma unroll
  for (int jj = 0; jj < 4; ++jj)
    tile[ty + jj * 8][tx] = s[(size_t)(k0 + ty + jj * 8) * DMODEL + n0 + tx];
  __syncthreads();
#pragma unroll
  for (int jj = 0; jj < 4; ++jj)
    d[(size_t)(n0 + ty + jj * 8) * DMODEL + k0 + tx] = f2bf(tile[tx][ty + jj * 8]);
}

// ------------------------------------------------------------- GEMM core
// 128x256 tile, BK=32, 4 waves (2x2), 2-phase double-buffer.
// 32 MFMAs per barrier-pair. As: 2x4096 shorts, Bs: 2x8192 shorts (48KB).
static __device__ __forceinline__ void gemm_core(
    short* As, short* Bs,
    const short* __restrict__ A, const short* __restrict__ Bt,
    const float* __restrict__ bias, void* __restrict__ outp,
    int rowbase, int colbase, int M, int Nn, int mode)
{
  const int K = DMODEL;
  int tid = threadIdx.x;
  int wid = tid >> 6, lane = tid & 63;
  int lg = lane >> 4, lq = lane & 15;
  int wm = wid >> 1, wn = wid & 1;

  f32x4 acc[4][8];
#pragma unroll
  for (int i = 0; i < 4; ++i)
#pragma unroll
    for (int j = 0; j < 8; ++j) acc[i][j] = (f32x4){0.f, 0.f, 0.f, 0.f};

  int srow = tid >> 2;
  int scol = (tid & 3) * 8;
  int ar0 = min(rowbase + srow, M - 1);
  int ar1 = min(rowbase + 64 + srow, M - 1);
  const short* Ag0 = A + (size_t)ar0 * K + scol;
  const short* Ag1 = A + (size_t)ar1 * K + scol;
  const short* Bg[4];
#pragma unroll
  for (int s = 0; s < 4; ++s) {
    int br = min(colbase + s * 64 + srow, Nn - 1);
    Bg[s] = Bt + (size_t)br * K + scol;
  }

  auto stage = [&](int kt, int buf) __attribute__((always_inline)) {
    short* Ab = As + buf * 4096;
    short* Bb = Bs + buf * 8192;
    gl_lds16(Ag0 + kt, Ab + wid * 512);
    gl_lds16(Ag1 + kt, Ab + 2048 + wid * 512);
#pragma unroll
    for (int s = 0; s < 4; ++s)
      gl_lds16(Bg[s] + kt, Bb + s * 2048 + wid * 512);
  };

  stage(0, 0);
  __syncthreads();
  int cur = 0;
  for (int kt = 0; kt < K; kt += 32) {
    if (kt + 32 < K) stage(kt + 32, cur ^ 1);
    const short* Ac = As + cur * 4096;
    const short* Bc = Bs + cur * 8192;
    bf16x8 aFrag[4], bFrag[8];
#pragma unroll
    for (int mi = 0; mi < 4; ++mi)
      aFrag[mi] = *(const bf16x8*)&Ac[(wm * 64 + mi * 16 + lq) * 32 + lg * 8];
#pragma unroll
    for (int ni = 0; ni < 8; ++ni)
      bFrag[ni] = *(const bf16x8*)&Bc[(wn * 128 + ni * 16 + lq) * 32 + lg * 8];
    __builtin_amdgcn_s_setprio(1);
#pragma unroll
    for (int mi = 0; mi < 4; ++mi)
#pragma unroll
      for (int ni = 0; ni < 8; ++ni)
        acc[mi][ni] = __builtin_amdgcn_mfma_f32_16x16x32_bf16(aFrag[mi], bFrag[ni], acc[mi][ni], 0, 0, 0);
    __builtin_amdgcn_s_setprio(0);
    __syncthreads();
    cur ^= 1;
  }

#pragma unroll
  for (int mi = 0; mi < 4; ++mi) {
    int rowq = rowbase + wm * 64 + mi * 16 + lg * 4;
#pragma unroll
    for (int r = 0; r < 4; ++r) {
      int row = rowq + r;
      if (row < M) {
        if (mode == 2) {
          float bb = bias[row];
#pragma unroll
          for (int ni = 0; ni < 8; ++ni) {
            int col = colbase + wn * 128 + ni * 16 + lq;
            if (col < Nn) {
              int b = col / NTOK, n = col - b * NTOK;
              float v = acc[mi][ni][r] + bb;
              ((short*)outp)[((size_t)b * DMODEL + row) * NTOK + n] = f2bf(v);
            }
          }
        } else {
          int bb = row / NTOK;
          int nn = row - bb * NTOK;
#pragma unroll
          for (int ni = 0; ni < 8; ++ni) {
            int col = colbase + wn * 128 + ni * 16 + lq;
            float v = acc[mi][ni][r] + bias[col];
            if (mode == 0) {
              ((float*)outp)[(size_t)row * DMODEL + col] = v;
            } else {
              ((short*)outp)[(((size_t)(bb * NUM_HEADS + (col >> 6)) * NTOK + nn) << 6) + (col & 63)] = f2bf(v);
            }
          }
        }
      }
    }
  }
}

// fused Q-proj / K-proj / V^T-proj.
// Q/K: 99 rowtiles x 3 coltiles = 297 each; V^T: 6 rowtiles x 50 coltiles = 300.
__global__ __launch_bounds__(256) void gemm_qkv_kernel(
    const short* __restrict__ Pq, const short* __restrict__ WqT,
    const float* __restrict__ bq, short* __restrict__ qhd,
    const short* __restrict__ Pk, const short* __restrict__ WkT,
    const float* __restrict__ bk, short* __restrict__ khd,
    const short* __restrict__ WvT, const short* __restrict__ Pv,
    const float* __restrict__ bv, short* __restrict__ vtg)
{
  __shared__ short As[2 * 4096];
  __shared__ short Bs[2 * 8192];
  const int NWG = 894;
  int lid = xcd_chunk(blockIdx.x, NWG);
  if (lid < 594) {
    int which = lid / 297;
    int sub = lid - which * 297;
    int rowbase = (sub / 3) * 128;     // col fastest: 3 consecutive share A panel
    int colbase = (sub % 3) * 256;
    gemm_core(As, Bs,
              which ? Pk : Pq, which ? WkT : WqT,
              which ? bk : bq, which ? (void*)khd : (void*)qhd,
              rowbase, colbase, BATCH * NTOK, DMODEL, 1);
  } else {
    int sub = lid - 594;
    int rowbase = (sub % 6) * 128;     // A (WvT) fastest: 6 consecutive share B panel
    int colbase = (sub / 6) * 256;
    gemm_core(As, Bs, WvT, Pv, bv, (void*)vtg,
              rowbase, colbase, DMODEL, BATCH * NTOK, 2);
  }
}

// final projection: 99 x 3 = 297 blocks
__global__ __launch_bounds__(256) void gemm_proj_kernel(
    const short* __restrict__ Afin, const short* __restrict__ WpT,
    const float* __restrict__ bp, float* __restrict__ outp)
{
  __shared__ short As[2 * 4096];
  __shared__ short Bs[2 * 8192];
  const int NWG = 297;
  int lid = xcd_chunk(blockIdx.x, NWG);
  int rowbase = (lid / 3) * 128;
  int colbase = (lid % 3) * 256;
  gemm_core(As, Bs, Afin, WpT, bp, (void*)outp,
            rowbase, colbase, BATCH * NTOK, DMODEL, 0);
}

// -------------------------------------------------------- rel-pos bias tables
__global__ __launch_bounds__(256) void relbias_kernel(
    const short* __restrict__ qh, const float* __restrict__ rph,
    const float* __restrict__ rpw, short* __restrict__ RelHt, short* __restrict__ RelWt)
{
  int line = blockIdx.x;   // i (mode0) or j (mode1)
  int bh = blockIdx.y;
  int mode = blockIdx.z;
  __shared__ __align__(16) float qt_s[28 * 68];
  __shared__ __align__(16) float rt_s[28 * 68];
  int tid = threadIdx.x;
  const float* rp = (mode == 0) ? rph : rpw;
  for (int idx = tid; idx < 28 * 64; idx += 256) {
    int rr = idx >> 6, c = idx & 63;
    int qi = (mode == 0) ? (1 + line * PHDIM + rr) : (1 + rr * PHDIM + line);
    qt_s[rr * 68 + c] = bf2f(qh[((size_t)bh * NTOK + qi) * HEAD_DIM + c]);
    rt_s[rr * 68 + c] = rp[(line - rr + 27) * HEAD_DIM + c];
  }
  __syncthreads();
  short* dst = (mode == 0) ? RelHt : RelWt;
  for (int o = tid; o < 784; o += 256) {
    int kk = o / PHDIM, rr = o - kk * PHDIM;
    const f32x4* qa = (const f32x4*)&qt_s[rr * 68];
    const f32x4* ra = (const f32x4*)&rt_s[kk * 68];
    f32x4 a4 = (f32x4){0.f, 0.f, 0.f, 0.f};
#pragma unroll
    for (int i = 0; i < 16; ++i) a4 += qa[i] * ra[i];
    float s = (a4[0] + a4[1] + a4[2] + a4[3]) * LOG2E;
    int qrow = (mode == 0) ? (line * PHDIM + rr) : (rr * PHDIM + line);
    dst[((size_t)bh * PHDIM + kk) * 784 + qrow] = f2bf(s);
  }
}

// ------------------------------------------------------------ flash attention
// flash5 (R7 proven): sigma-permuted K rows, lane-local P, single-buffered.
__global__ __launch_bounds__(256) void flash5_kernel(
    const short* __restrict__ qh, const short* __restrict__ kh, const short* __restrict__ vtg,
    const short* __restrict__ RelHt, const short* __restrict__ RelWt,
    short* __restrict__ Afin)
{
  int id = blockIdx.x;
  int slot = id >> 3;
  int bh = (id & 7) * 24 + slot / 13;   // all 13 q-tiles of a bh on one XCD
  int qt = slot - (slot / 13) * 13;
  int qbase = qt * 64;
  int tid = threadIdx.x, wid = tid >> 6, lane = tid & 63;
  int lg = lane >> 4, lq = lane & 15;

  __shared__ __align__(16) short ks[64 * 64];      // sigma-permuted K rows, chunk-swizzled
  __shared__ __align__(16) short vt[64 * 64];      // V^T[d][key], key-chunks swizzled by d&7
  __shared__ __align__(16) float relh_t[28][64];   // [ki][q_local], log2e-scaled
  __shared__ __align__(16) float relw_t[28][64];
  __shared__ __align__(16) float axl[4][16];

  for (int idx = tid; idx < 28 * 64; idx += 256) {
    int kk = idx >> 6, ql = idx & 63;
    int qi = qbase + ql;
    float rh = 0.f, rw = 0.f;
    if (qi >= 1 && qi < NTOK) {
      rh = bf2f(RelHt[((size_t)bh * PHDIM + kk) * 784 + qi - 1]);
      rw = bf2f(RelWt[((size_t)bh * PHDIM + kk) * 784 + qi - 1]);
    }
    relh_t[kk][ql] = rh; relw_t[kk][ql] = rw;
  }

  int qi0 = qbase + wid * 16 + lq;
  int qiq = min(qi0, NTOK - 1);
  const short* qrow = qh + ((size_t)bh * NTOK + qiq) * HEAD_DIM;
  bf16x8 bq0 = *(const bf16x8*)(qrow + lg * 8);
  bf16x8 bq1 = *(const bf16x8*)(qrow + 32 + lg * 8);

  float m_l = -3e30f, l_l = 0.f;
  f32x4 acc[4];
#pragma unroll
  for (int ch = 0; ch < 4; ++ch) acc[ch] = (f32x4){0.f, 0.f, 0.f, 0.f};

  const float scale2 = 0.125f * LOG2E;
  int q_local = wid * 16 + lq;
  const short* kbase = kh + (size_t)bh * NTOK * HEAD_DIM;
  const short* vbase = vtg + (size_t)bh * (size_t)HEAD_DIM * NTOK;

  int c0 = tid, c1 = 256 + tid;
  int rr0 = c0 >> 3, j0 = c0 & 7;
  int rr1 = c1 >> 3, j1 = c1 & 7;
  int koff0 = ((rr0 & 15) >> 2) * 16 + (rr0 >> 4) * 4 + (rr0 & 3);
  int koff1 = ((rr1 & 15) >> 2) * 16 + (rr1 >> 4) * 4 + (rr1 & 3);
  int ksw0 = (j0 ^ (rr0 & 7)) << 3;
  int ksw1 = (j1 ^ (rr1 & 7)) << 3;
  int vsw0 = (j0 ^ (rr0 & 7)) << 3;
  int vsw1 = (j1 ^ (rr1 & 7)) << 3;
  const short* vsrc0 = vbase + (size_t)rr0 * NTOK + vsw0;
  const short* vsrc1 = vbase + (size_t)rr1 * NTOK + vsw1;

  auto step_body = [&](int kvb, bool first, bool last) __attribute__((always_inline)) {
    __syncthreads();
    gl_lds16(kbase + (size_t)min(kvb + koff0, NTOK - 1) * HEAD_DIM + ksw0, ks + wid * 512);
    gl_lds16(kbase + (size_t)min(kvb + koff1, NTOK - 1) * HEAD_DIM + ksw1, ks + 2048 + wid * 512);
    gl_lds16(vsrc0 + kvb, vt + wid * 512);
    gl_lds16(vsrc1 + kvb, vt + 2048 + wid * 512);
    __syncthreads();

    int base = kvb + 16 * lg;
    int km1 = base - 1;
    int t = max(km1, 0);
    int ki = t / PHDIM;
    int kj = t - ki * PHDIM;
    if (km1 < 0) kj = -1;

    float p[16];
#pragma unroll
    for (int kt = 0; kt < 4; ++kt) {
      int kl = kt * 16 + lq;
      const char* kp = (const char*)ks + kl * 128;
      int swz = kl & 7;
      bf16x8 aK0 = *(const bf16x8*)(kp + ((lg ^ swz) << 4));
      bf16x8 aK1 = *(const bf16x8*)(kp + (((lg + 4) ^ swz) << 4));
      f32x4 s = (f32x4){0.f, 0.f, 0.f, 0.f};
      __builtin_amdgcn_s_setprio(1);
      s = __builtin_amdgcn_mfma_f32_16x16x32_bf16(aK0, bq0, s, 0, 0, 0);
      s = __builtin_amdgcn_mfma_f32_16x16x32_bf16(aK1, bq1, s, 0, 0, 0);
      __builtin_amdgcn_s_setprio(0);
#pragma unroll
      for (int r = 0; r < 4; ++r) {
        int i = kt * 4 + r;
        float v = s[r] * scale2;
        if (first) {
          int key = base + i;
          if (key >= 1) v += relh_t[ki][q_local] + relw_t[kj][q_local];
        } else if (last) {
          int key = base + i;
          v += relh_t[ki][q_local] + relw_t[kj][q_local];
          if (key >= NTOK) v = -3e30f;
        } else {
          v += relh_t[ki][q_local] + relw_t[kj][q_local];
        }
        p[i] = v;
        ++kj;
        if (kj == PHDIM) { kj = 0; ++ki; }
      }
    }

    float pm = p[0];
#pragma unroll
    for (int i = 1; i < 16; ++i) pm = fmaxf(pm, p[i]);
    pm = fmaxf(pm, __shfl_xor(pm, 16));
    pm = fmaxf(pm, __shfl_xor(pm, 32));
    if (!__all(pm - m_l <= 11.5f)) {
      float mnew = fmaxf(m_l, pm);
      float alpha = fexp2(m_l - mnew);
      m_l = mnew;
      l_l *= alpha;
      if (lg == 0) axl[wid][lq] = alpha;
      f32x4 av = *(const f32x4*)&axl[wid][lg * 4];
#pragma unroll
      for (int ch = 0; ch < 4; ++ch)
#pragma unroll
        for (int r = 0; r < 4; ++r) acc[ch][r] *= av[r];
    }
    float ps = 0.f;
#pragma unroll
    for (int i = 0; i < 16; ++i) { p[i] = fexp2(p[i] - m_l); ps += p[i]; }
    ps += __shfl_xor(ps, 16);
    ps += __shfl_xor(ps, 32);
    l_l += ps;

    bf16x8 pa0, pa1;
#pragma unroll
    for (int j = 0; j < 4; ++j) {
      unsigned u0, u1, v0, v1;
      __builtin_memcpy(&u0, &p[2 * j], 4);
      __builtin_memcpy(&u1, &p[2 * j + 1], 4);
      __builtin_memcpy(&v0, &p[8 + 2 * j], 4);
      __builtin_memcpy(&v1, &p[8 + 2 * j + 1], 4);
      ((unsigned*)&pa0)[j] = (u0 >> 16) | (u1 & 0xFFFF0000u);
      ((unsigned*)&pa1)[j] = (v0 >> 16) | (v1 & 0xFFFF0000u);
    }
    __builtin_amdgcn_s_setprio(1);
#pragma unroll
    for (int ch = 0; ch < 4; ++ch) {
      int d = ch * 16 + lq;
      const char* vrow = (const char*)vt + d * 128;
      int swz = lq & 7;
      bf16x8 bv0 = *(const bf16x8*)(vrow + (((2 * lg + 0) ^ swz) << 4));
      bf16x8 bv1 = *(const bf16x8*)(vrow + (((2 * lg + 1) ^ swz) << 4));
      acc[ch] = __builtin_amdgcn_mfma_f32_16x16x32_bf16(pa0, bv0, acc[ch], 0, 0, 0);
      acc[ch] = __builtin_amdgcn_mfma_f32_16x16x32_bf16(pa1, bv1, acc[ch], 0, 0, 0);
    }
    __builtin_amdgcn_s_setprio(0);
  };

  step_body(0, true, false);
  for (int step = 1; step < 12; ++step) step_body(step * 64, false, false);
  step_body(12 * 64, false, true);

  if (lg == 0) axl[wid][lq] = l_l;
  f32x4 lv = *(const f32x4*)&axl[wid][lg * 4];
  int b = bh / NUM_HEADS, h = bh - b * NUM_HEADS;
#pragma unroll
  for (int r = 0; r < 4; ++r) {
    int qi = qbase + wid * 16 + lg * 4 + r;
    if (qi < NTOK) {
      float inv = 1.f / lv[r];
#pragma unroll
      for (int ch = 0; ch < 4; ++ch) {
        int d = ch * 16 + lq;
        float o = acc[ch][r] * inv + bf2f(qh[((size_t)bh * NTOK + qi) * HEAD_DIM + d]);
        Afin[((size_t)b * NTOK + qi) * DMODEL + h * HEAD_DIM + d] = f2bf(o);
      }
    }
  }
}

// ------------------------------------------------------------------- launcher
extern "C" void kernel_launch(void* const* d_in, const int* in_sizes, int n_in,
                              void* d_out, int out_size, void* d_ws, size_t ws_size,
                              hipStream_t stream)
{
  (void)in_sizes; (void)n_in; (void)out_size; (void)ws_size;
  const float* x   = (const float*)d_in[0];
  const float* pqw = (const float*)d_in[1];
  const float* pkw = (const float*)d_in[2];
  const float* pvw = (const float*)d_in[3];
  const float* gq  = (const float*)d_in[4];
  const float* bq_ = (const float*)d_in[5];
  const float* gk  = (const float*)d_in[6];
  const float* bk_ = (const float*)d_in[7];
  const float* gv  = (const float*)d_in[8];
  const float* bv_ = (const float*)d_in[9];
  const float* wq  = (const float*)d_in[10];
  const float* bqp = (const float*)d_in[11];
  const float* wk  = (const float*)d_in[12];
  const float* bkp = (const float*)d_in[13];
  const float* wv  = (const float*)d_in[14];
  const float* bvp = (const float*)d_in[15];
  const float* wp  = (const float*)d_in[16];
  const float* bpp = (const float*)d_in[17];
  const float* rph = (const float*)d_in[18];
  const float* rpw = (const float*)d_in[19];

  char* ws = (char*)d_ws;
  size_t off = 0;
  auto alloc = [&](size_t bytes) -> void* {
    void* p = ws + off; off += (bytes + 255) & ~(size_t)255; return p;
  };
  const size_t MROWS = (size_t)BATCH * NTOK;   // 12560
  short* Pq  = (short*)alloc(MROWS * DMODEL * 2);
  short* Pk  = (short*)alloc(MROWS * DMODEL * 2);
  short* Pv  = (short*)alloc(MROWS * DMODEL * 2);
  short* WqT = (short*)alloc((size_t)DMODEL * DMODEL * 2);
  short* WkT = (short*)alloc((size_t)DMODEL * DMODEL * 2);
  short* WvT = (short*)alloc((size_t)DMODEL * DMODEL * 2);
  short* WpT = (short*)alloc((size_t)DMODEL * DMODEL * 2);
  short* qhd = (short*)alloc(MROWS * DMODEL * 2 + 4096);
  short* khd = (short*)alloc(MROWS * DMODEL * 2 + 4096);
  short* vtg = (short*)alloc(MROWS * DMODEL * 2 + 8192);  // transposed V
  short* RelHt = (short*)alloc((size_t)BHCNT * 784 * 28 * 2);
  short* RelWt = (short*)alloc((size_t)BHCNT * 784 * 28 * 2);
  short* Afin = (short*)alloc(MROWS * DMODEL * 2);

  pool_ln_kernel<<<dim3(16 * 197), 192, 0, stream>>>(
      x, pqw, pkw, pvw, gq, bq_, gk, bk_, gv, bv_, Pq, Pk, Pv);
  trans_kernel<<<dim3(24, 24, 4), dim3(32, 8), 0, stream>>>(
      wq, wk, wv, wp, WqT, WkT, WvT, WpT);
  gemm_qkv_kernel<<<dim3(894), 256, 0, stream>>>(
      Pq, WqT, bqp, qhd, Pk, WkT, bkp, khd, WvT, Pv, bvp, vtg);
  relbias_kernel<<<dim3(28, BHCNT, 2), 256, 0, stream>>>(qhd, rph, rpw, RelHt, RelWt);
  flash5_kernel<<<dim3(2496), 256, 0, stream>>>(qhd, khd, vtg, RelHt, RelWt, Afin);
  gemm_proj_kernel<<<dim3(297), 256, 0, stream>>>(Afin, WpT, bpp, (float*)d_out);
}

// Round 11
// 376.692 us; speedup vs baseline: 1.4517x; 1.4517x over previous
//
#include <hip/hip_runtime.h>
#include <stdint.h>

#define NUM_HEADS 12
#define HEAD_DIM  64
#define HWDIM     56
#define PHDIM     28
#define NTOK      785     // 28*28+1
#define NIN       3137    // 56*56+1
#define BATCH     16
#define DMODEL    768
#define BHCNT     192     // BATCH*NUM_HEADS
#define LOG2E     1.44269504f

typedef __attribute__((ext_vector_type(8))) short bf16x8;
typedef __attribute__((ext_vector_type(4))) short s16x4;
typedef __attribute__((ext_vector_type(4))) float f32x4;

static __device__ __forceinline__ float bf2f(short s) {
  unsigned u = ((unsigned)(unsigned short)s) << 16;
  float f; __builtin_memcpy(&f, &u, 4); return f;
}
static __device__ __forceinline__ short f2bf(float f) {
  unsigned u; __builtin_memcpy(&u, &f, 4);
  unsigned r = u + 0x7FFFu + ((u >> 16) & 1u);
  return (short)(r >> 16);
}
static __device__ __forceinline__ float fexp2(float x) {
#if defined(__has_builtin)
#if __has_builtin(__builtin_amdgcn_exp2f)
  return __builtin_amdgcn_exp2f(x);
#else
  return exp2f(x);
#endif
#else
  return exp2f(x);
#endif
}

// bijective XCD chunking (m204)
static __device__ __forceinline__ int xcd_chunk(int orig, int nwg) {
  int xcd = orig & 7;
  int within = orig >> 3;
  int q = nwg >> 3, r = nwg & 7;
  int base = (xcd < r) ? xcd * (q + 1) : r * (q + 1) + (xcd - r) * q;
  return base + within;
}

#if defined(__has_builtin)
#if __has_builtin(__builtin_amdgcn_global_load_lds)
#define HAVE_GLLDS 1
#endif
#endif

static __device__ __forceinline__ void gl_lds16(const short* g, short* l) {
#ifdef HAVE_GLLDS
  __builtin_amdgcn_global_load_lds(
      (const __attribute__((address_space(1))) void*)g,
      (__attribute__((address_space(3))) void*)l, 16, 0, 0);
#else
  int lane = threadIdx.x & 63;
  *(bf16x8*)(l + lane * 8) = *(const bf16x8*)g;
#endif
}

// ---------------------------------------------------------------- pool + LN
__global__ __launch_bounds__(192) void pool_ln_kernel(
    const float* __restrict__ x,
    const float* __restrict__ wq9, const float* __restrict__ wk9, const float* __restrict__ wv9,
    const float* __restrict__ gq, const float* __restrict__ bq,
    const float* __restrict__ gk, const float* __restrict__ bk,
    const float* __restrict__ gv, const float* __restrict__ bv,
    short* __restrict__ Pq, short* __restrict__ Pk, short* __restrict__ Pv)
{
  __shared__ __align__(16) float wt_s[3][9][64];   // [conv][tap][c]
  int tid = threadIdx.x;
  int blk = blockIdx.x;
  int b = blk / 197;
  int n0 = (blk - b * 197) * 4;

  for (int idx = tid; idx < 3 * 576; idx += 192) {
    int conv = idx / 576, rem = idx - conv * 576;
    int c = rem / 9, tap = rem - c * 9;
    const float* wsrc = (conv == 0) ? wq9 : (conv == 1) ? wk9 : wv9;
    wt_s[conv][tap][c] = wsrc[c * 9 + tap];
  }
  __syncthreads();

  int ch0 = tid * 4;
  int c4 = ch0 & 63;
  f32x4 g_q = *(const f32x4*)&gq[c4], b_q = *(const f32x4*)&bq[c4];
  f32x4 g_k = *(const f32x4*)&gk[c4], b_k = *(const f32x4*)&bk[c4];
  f32x4 g_v = *(const f32x4*)&gv[c4], b_v = *(const f32x4*)&bv[c4];

  for (int tt = 0; tt < 4; ++tt) {
    int n = n0 + tt;
    if (n >= NTOK) break;
    f32x4 aq = (f32x4){0.f, 0.f, 0.f, 0.f}, ak = aq, av = aq;
    if (n == 0) {
      f32x4 x4 = *(const f32x4*)&x[((size_t)b * NIN) * DMODEL + ch0];
      aq = ak = av = x4;
    } else {
      int s = n - 1;
      int i = s / PHDIM, j = s - i * PHDIM;
#pragma unroll
      for (int di = 0; di < 3; ++di) {
        int ii = 2 * i - 1 + di;
        if (ii < 0 || ii >= HWDIM) continue;
#pragma unroll
        for (int dj = 0; dj < 3; ++dj) {
          int jj = 2 * j - 1 + dj;
          if (jj < 0 || jj >= HWDIM) continue;
          f32x4 x4 = *(const f32x4*)&x[((size_t)b * NIN + 1 + ii * HWDIM + jj) * DMODEL + ch0];
          int tap = di * 3 + dj;
          f32x4 w0 = *(const f32x4*)&wt_s[0][tap][c4];
          f32x4 w1 = *(const f32x4*)&wt_s[1][tap][c4];
          f32x4 w2 = *(const f32x4*)&wt_s[2][tap][c4];
          aq += w0 * x4; ak += w1 * x4; av += w2 * x4;
        }
      }
    }
    size_t obase = ((size_t)b * NTOK + n) * DMODEL + ch0;
    {
      float sm = aq[0] + aq[1] + aq[2] + aq[3];
#pragma unroll
      for (int m = 1; m < 16; m <<= 1) sm += __shfl_xor(sm, m);
      float mn = sm * (1.f / 64.f);
      f32x4 d = aq - mn;
      float vs = d[0]*d[0] + d[1]*d[1] + d[2]*d[2] + d[3]*d[3];
#pragma unroll
      for (int m = 1; m < 16; m <<= 1) vs += __shfl_xor(vs, m);
      float rs = rsqrtf(vs * (1.f / 64.f) + 1e-5f);
      s16x4 o;
#pragma unroll
      for (int e = 0; e < 4; ++e) o[e] = f2bf(d[e] * rs * g_q[e] + b_q[e]);
      *(s16x4*)&Pq[obase] = o;
    }
    {
      float sm = ak[0] + ak[1] + ak[2] + ak[3];
#pragma unroll
      for (int m = 1; m < 16; m <<= 1) sm += __shfl_xor(sm, m);
      float mn = sm * (1.f / 64.f);
      f32x4 d = ak - mn;
      float vs = d[0]*d[0] + d[1]*d[1] + d[2]*d[2] + d[3]*d[3];
#pragma unroll
      for (int m = 1; m < 16; m <<= 1) vs += __shfl_xor(vs, m);
      float rs = rsqrtf(vs * (1.f / 64.f) + 1e-5f);
      s16x4 o;
#pragma unroll
      for (int e = 0; e < 4; ++e) o[e] = f2bf(d[e] * rs * g_k[e] + b_k[e]);
      *(s16x4*)&Pk[obase] = o;
    }
    {
      float sm = av[0] + av[1] + av[2] + av[3];
#pragma unroll
      for (int m = 1; m < 16; m <<= 1) sm += __shfl_xor(sm, m);
      float mn = sm * (1.f / 64.f);
      f32x4 d = av - mn;
      float vs = d[0]*d[0] + d[1]*d[1] + d[2]*d[2] + d[3]*d[3];
#pragma unroll
      for (int m = 1; m < 16; m <<= 1) vs += __shfl_xor(vs, m);
      float rs = rsqrtf(vs * (1.f / 64.f) + 1e-5f);
      s16x4 o;
#pragma unroll
      for (int e = 0; e < 4; ++e) o[e] = f2bf(d[e] * rs * g_v[e] + b_v[e]);
      *(s16x4*)&Pv[obase] = o;
    }
  }
}

// ------------------------------------------------- weight transpose fp32->bf16
__global__ __launch_bounds__(256) void trans_kernel(
    const float* __restrict__ s0, const float* __restrict__ s1,
    const float* __restrict__ s2, const float* __restrict__ s3,
    short* __restrict__ d0, short* __restrict__ d1,
    short* __restrict__ d2, short* __restrict__ d3)
{
  __shared__ float tile[32][33];
  int z = blockIdx.z;
  const float* s = (z == 0) ? s0 : (z == 1) ? s1 : (z == 2) ? s2 : s3;
  short* d = (z == 0) ? d0 : (z == 1) ? d1 : (z == 2) ? d2 : d3;
  int k0 = blockIdx.x * 32, n0 = blockIdx.y * 32;
  int tx = threadIdx.x, ty = threadIdx.y;   // 32 x 8
#pragma unroll
  for (int jj = 0; jj < 4; ++jj)
    tile[ty + jj * 8][tx] = s[(size_t)(k0 + ty + jj * 8) * DMODEL + n0 + tx];
  __syncthreads();
#pragma unroll
  for (int jj = 0; jj < 4; ++jj)
    d[(size_t)(n0 + ty + jj * 8) * DMODEL + k0 + tx] = f2bf(tile[tx][ty + jj * 8]);
}

// ------------------------------------------------------------- GEMM core (R8)
// 128x128, BK=32, 2-phase dbuf, single barrier per K-step.
static __device__ __forceinline__ void gemm_core(
    short* As, short* Bs,
    const short* __restrict__ A, const short* __restrict__ Bt,
    const float* __restrict__ bias, void* __restrict__ outp,
    int rowbase, int colbase, int M, int Nn, int mode)
{
  const int K = DMODEL;
  int tid = threadIdx.x;
  int wid = tid >> 6, lane = tid & 63;
  int lg = lane >> 4, lq = lane & 15;
  int wm = wid >> 1, wn = wid & 1;

  f32x4 acc[4][4];
#pragma unroll
  for (int i = 0; i < 4; ++i)
#pragma unroll
    for (int j = 0; j < 4; ++j) acc[i][j] = (f32x4){0.f, 0.f, 0.f, 0.f};

  int srow = tid >> 2;
  int scol = (tid & 3) * 8;
  int ar0 = min(rowbase + srow, M - 1);
  int ar1 = min(rowbase + 64 + srow, M - 1);
  int br0 = min(colbase + srow, Nn - 1);
  int br1 = min(colbase + 64 + srow, Nn - 1);
  const short* Ag0 = A + (size_t)ar0 * K + scol;
  const short* Ag1 = A + (size_t)ar1 * K + scol;
  const short* Bg0 = Bt + (size_t)br0 * K + scol;
  const short* Bg1 = Bt + (size_t)br1 * K + scol;

  auto stage = [&](int kt, int buf) __attribute__((always_inline)) {
    short* Ab = As + buf * 4096;
    short* Bb = Bs + buf * 4096;
    gl_lds16(Ag0 + kt, Ab + wid * 512);
    gl_lds16(Ag1 + kt, Ab + 2048 + wid * 512);
    gl_lds16(Bg0 + kt, Bb + wid * 512);
    gl_lds16(Bg1 + kt, Bb + 2048 + wid * 512);
  };

  stage(0, 0);
  __syncthreads();
  int cur = 0;
  for (int kt = 0; kt < K; kt += 32) {
    if (kt + 32 < K) stage(kt + 32, cur ^ 1);
    const short* Ac = As + cur * 4096;
    const short* Bc = Bs + cur * 4096;
    bf16x8 aFrag[4], bFrag[4];
#pragma unroll
    for (int mi = 0; mi < 4; ++mi)
      aFrag[mi] = *(const bf16x8*)&Ac[(wm * 64 + mi * 16 + lq) * 32 + lg * 8];
#pragma unroll
    for (int ni = 0; ni < 4; ++ni)
      bFrag[ni] = *(const bf16x8*)&Bc[(wn * 64 + ni * 16 + lq) * 32 + lg * 8];
    __builtin_amdgcn_s_setprio(1);
#pragma unroll
    for (int mi = 0; mi < 4; ++mi)
#pragma unroll
      for (int ni = 0; ni < 4; ++ni)
        acc[mi][ni] = __builtin_amdgcn_mfma_f32_16x16x32_bf16(aFrag[mi], bFrag[ni], acc[mi][ni], 0, 0, 0);
    __builtin_amdgcn_s_setprio(0);
    __syncthreads();
    cur ^= 1;
  }

#pragma unroll
  for (int mi = 0; mi < 4; ++mi) {
    int rowq = rowbase + wm * 64 + mi * 16 + lg * 4;
#pragma unroll
    for (int r = 0; r < 4; ++r) {
      int row = rowq + r;
      if (row < M) {
        if (mode == 2) {
          float bb = bias[row];
#pragma unroll
          for (int ni = 0; ni < 4; ++ni) {
            int col = colbase + wn * 64 + ni * 16 + lq;
            if (col < Nn) {
              int b = col / NTOK, n = col - b * NTOK;
              float v = acc[mi][ni][r] + bb;
              ((short*)outp)[((size_t)b * DMODEL + row) * NTOK + n] = f2bf(v);
            }
          }
        } else {
          int bb = row / NTOK;
          int nn = row - bb * NTOK;
#pragma unroll
          for (int ni = 0; ni < 4; ++ni) {
            int col = colbase + wn * 64 + ni * 16 + lq;
            float v = acc[mi][ni][r] + bias[col];
            if (mode == 0) {
              ((float*)outp)[(size_t)row * DMODEL + col] = v;
            } else {
              ((short*)outp)[(((size_t)(bb * NUM_HEADS + (col >> 6)) * NTOK + nn) << 6) + (col & 63)] = f2bf(v);
            }
          }
        }
      }
    }
  }
}

__global__ __launch_bounds__(256) void gemm_qkv_kernel(
    const short* __restrict__ Pq, const short* __restrict__ WqT,
    const float* __restrict__ bq, short* __restrict__ qhd,
    const short* __restrict__ Pk, const short* __restrict__ WkT,
    const float* __restrict__ bk, short* __restrict__ khd,
    const short* __restrict__ WvT, const short* __restrict__ Pv,
    const float* __restrict__ bv, short* __restrict__ vtg)
{
  __shared__ short As[2 * 4096];
  __shared__ short Bs[2 * 4096];
  const int NWG = 1782;
  int lid = xcd_chunk(blockIdx.x, NWG);
  if (lid < 1188) {
    int which = lid / 594;
    int sub = lid - which * 594;
    int rowbase = (sub / 6) * 128;
    int colbase = (sub % 6) * 128;
    gemm_core(As, Bs,
              which ? Pk : Pq, which ? WkT : WqT,
              which ? bk : bq, which ? (void*)khd : (void*)qhd,
              rowbase, colbase, BATCH * NTOK, DMODEL, 1);
  } else {
    int sub = lid - 1188;
    int rowbase = (sub % 6) * 128;
    int colbase = (sub / 6) * 128;
    gemm_core(As, Bs, WvT, Pv, bv, (void*)vtg,
              rowbase, colbase, DMODEL, BATCH * NTOK, 2);
  }
}

__global__ __launch_bounds__(256) void gemm_proj_kernel(
    const short* __restrict__ Afin, const short* __restrict__ WpT,
    const float* __restrict__ bp, float* __restrict__ outp)
{
  __shared__ short As[2 * 4096];
  __shared__ short Bs[2 * 4096];
  const int NWG = 594;
  int lid = xcd_chunk(blockIdx.x, NWG);
  int rowbase = (lid / 6) * 128;
  int colbase = (lid % 6) * 128;
  gemm_core(As, Bs, Afin, WpT, bp, (void*)outp,
            rowbase, colbase, BATCH * NTOK, DMODEL, 0);
}

// -------------------------------------------------------- augmented Q/K build
// qaug[bh][n][128]: [0:64) = scale2 * qhd ; [64:128) = 0 (relbias fills 64..119)
__global__ __launch_bounds__(256) void qaug_kernel(
    const short* __restrict__ qh, short* __restrict__ qaug)
{
  int t = threadIdx.x;
  size_t gr = (size_t)blockIdx.x * 16 + (t >> 4);
  int c = t & 15;
  bf16x8 o = {0, 0, 0, 0, 0, 0, 0, 0};
  if (c < 8) {
    bf16x8 v = *(const bf16x8*)(qh + gr * 64 + c * 8);
    const float s2 = 0.125f * LOG2E;
#pragma unroll
    for (int e = 0; e < 8; ++e) o[e] = f2bf(bf2f(v[e]) * s2);
  }
  *(bf16x8*)(qaug + gr * 128 + c * 8) = o;
}

// kaug[bh][n][128]: [0:64) = khd ; [64+ki]=1 ; [92+kj]=1 ; else 0 (n=0: aug=0)
__global__ __launch_bounds__(256) void kaug_kernel(
    const short* __restrict__ kh, short* __restrict__ kaug)
{
  int t = threadIdx.x;
  size_t gr = (size_t)blockIdx.x * 16 + (t >> 4);
  int c = t & 15;
  int n = (int)(gr % NTOK);
  bf16x8 o = {0, 0, 0, 0, 0, 0, 0, 0};
  if (c < 8) {
    o = *(const bf16x8*)(kh + gr * 64 + c * 8);
  } else if (n >= 1) {
    int km1 = n - 1;
    int ki = km1 / PHDIM, kj = km1 - (km1 / PHDIM) * PHDIM;
    int d0 = c * 8;
#pragma unroll
    for (int e = 0; e < 8; ++e) {
      int d = d0 + e;
      o[e] = (d == 64 + ki || d == 92 + kj) ? (short)0x3F80 : (short)0;
    }
  }
  *(bf16x8*)(kaug + gr * 128 + c * 8) = o;
}

// -------------------------------------------------------- rel-pos bias tables
// writes log2e-scaled bias rows directly into qaug dims [64:120)
__global__ __launch_bounds__(256) void relbias_kernel(
    const short* __restrict__ qh, const float* __restrict__ rph,
    const float* __restrict__ rpw, short* __restrict__ qaug)
{
  int line = blockIdx.x;   // i (mode0) or j (mode1)
  int bh = blockIdx.y;
  int mode = blockIdx.z;
  __shared__ __align__(16) float qt_s[28 * 68];
  __shared__ __align__(16) float rt_s[28 * 68];
  int tid = threadIdx.x;
  const float* rp = (mode == 0) ? rph : rpw;
  for (int idx = tid; idx < 28 * 64; idx += 256) {
    int rr = idx >> 6, c = idx & 63;
    int qi = (mode == 0) ? (1 + line * PHDIM + rr) : (1 + rr * PHDIM + line);
    qt_s[rr * 68 + c] = bf2f(qh[((size_t)bh * NTOK + qi) * HEAD_DIM + c]);
    rt_s[rr * 68 + c] = rp[(line - rr + 27) * HEAD_DIM + c];
  }
  __syncthreads();
  for (int o = tid; o < 784; o += 256) {
    int kk = o / PHDIM, rr = o - kk * PHDIM;
    const f32x4* qa = (const f32x4*)&qt_s[rr * 68];
    const f32x4* ra = (const f32x4*)&rt_s[kk * 68];
    f32x4 a4 = (f32x4){0.f, 0.f, 0.f, 0.f};
#pragma unroll
    for (int i = 0; i < 16; ++i) a4 += qa[i] * ra[i];
    float s = (a4[0] + a4[1] + a4[2] + a4[3]) * LOG2E;
    int qi = (mode == 0) ? (1 + line * PHDIM + rr) : (1 + rr * PHDIM + line);
    int dim = (mode == 0) ? (64 + kk) : (92 + kk);
    qaug[((size_t)bh * NTOK + qi) * 128 + dim] = f2bf(s);
  }
}

// ------------------------------------------------------------ flash attention
// augmented QK (bias inside MFMA); sigma-permuted K rows; lane-local P.
__global__ __launch_bounds__(256) void flash7_kernel(
    const short* __restrict__ qaug, const short* __restrict__ qh,
    const short* __restrict__ kaug, const short* __restrict__ vtg,
    short* __restrict__ Afin)
{
  int id = blockIdx.x;
  int slot = id >> 3;
  int bh = (id & 7) * 24 + slot / 13;   // all 13 q-tiles of a bh on one XCD
  int qt = slot - (slot / 13) * 13;
  int qbase = qt * 64;
  int tid = threadIdx.x, wid = tid >> 6, lane = tid & 63;
  int lg = lane >> 4, lq = lane & 15;

  __shared__ __align__(16) short ks[64 * 128];   // sigma-permuted K_aug rows (16 slots, swz rr&15)
  __shared__ __align__(16) short vt[64 * 64];    // V^T[d][key] (8 slots, swz d&7)
  __shared__ __align__(16) float axl[4][16];

  int qi0 = qbase + wid * 16 + lq;
  int qiq = min(qi0, NTOK - 1);
  const short* qrow = qaug + ((size_t)bh * NTOK + qiq) * 128;
  bf16x8 bq[4];
#pragma unroll
  for (int c = 0; c < 4; ++c) bq[c] = *(const bf16x8*)(qrow + c * 32 + lg * 8);

  float m_l = -3e30f, l_l = 0.f;
  f32x4 acc[4];
#pragma unroll
  for (int ch = 0; ch < 4; ++ch) acc[ch] = (f32x4){0.f, 0.f, 0.f, 0.f};

  const short* kbase = kaug + (size_t)bh * NTOK * 128;
  const short* vbase = vtg + (size_t)bh * (size_t)HEAD_DIM * NTOK;

  // K staging: 1024 chunks of 16B, 4 calls x (256 lanes)
  int koffK[4], kslot[4];
#pragma unroll
  for (int m = 0; m < 4; ++m) {
    int c = m * 256 + tid;
    int rr = c >> 4, j = c & 15;
    koffK[m] = ((rr & 15) >> 2) * 16 + (rr >> 4) * 4 + (rr & 3);
    kslot[m] = (j ^ (rr & 15)) << 3;
  }
  // V staging: 512 chunks, 2 calls
  int c0 = tid, c1 = 256 + tid;
  int vr0 = c0 >> 3, vj0 = c0 & 7;
  int vr1 = c1 >> 3, vj1 = c1 & 7;
  const short* vsrc0 = vbase + (size_t)vr0 * NTOK + ((vj0 ^ (vr0 & 7)) << 3);
  const short* vsrc1 = vbase + (size_t)vr1 * NTOK + ((vj1 ^ (vr1 & 7)) << 3);

  auto step_body = [&](int kvb, bool last) __attribute__((always_inline)) {
    __syncthreads();
#pragma unroll
    for (int m = 0; m < 4; ++m)
      gl_lds16(kbase + (size_t)min(kvb + koffK[m], NTOK - 1) * 128 + kslot[m],
               ks + m * 2048 + wid * 512);
    gl_lds16(vsrc0 + kvb, vt + wid * 512);
    gl_lds16(vsrc1 + kvb, vt + 2048 + wid * 512);
    __syncthreads();

    float p[16];
#pragma unroll
    for (int kt = 0; kt < 4; ++kt) {
      int kl = kt * 16 + lq;
      const char* kp = (const char*)ks + kl * 256;
      int swz = kl & 15;
      f32x4 s = (f32x4){0.f, 0.f, 0.f, 0.f};
      __builtin_amdgcn_s_setprio(1);
#pragma unroll
      for (int c = 0; c < 4; ++c) {
        bf16x8 aK = *(const bf16x8*)(kp + (((c * 4 + lg) ^ swz) << 4));
        s = __builtin_amdgcn_mfma_f32_16x16x32_bf16(aK, bq[c], s, 0, 0, 0);
      }
      __builtin_amdgcn_s_setprio(0);
#pragma unroll
      for (int r = 0; r < 4; ++r) {
        int i = kt * 4 + r;
        float v = s[r];
        if (last) {
          int key = kvb + 16 * lg + i;
          if (key >= NTOK) v = -3e30f;
        }
        p[i] = v;
      }
    }

    float pm = p[0];
#pragma unroll
    for (int i = 1; i < 16; ++i) pm = fmaxf(pm, p[i]);
    pm = fmaxf(pm, __shfl_xor(pm, 16));
    pm = fmaxf(pm, __shfl_xor(pm, 32));
    if (!__all(pm - m_l <= 11.5f)) {
      float mnew = fmaxf(m_l, pm);
      float alpha = fexp2(m_l - mnew);
      m_l = mnew;
      l_l *= alpha;
      if (lg == 0) axl[wid][lq] = alpha;
      f32x4 av = *(const f32x4*)&axl[wid][lg * 4];
#pragma unroll
      for (int ch = 0; ch < 4; ++ch)
#pragma unroll
        for (int r = 0; r < 4; ++r) acc[ch][r] *= av[r];
    }
    float ps = 0.f;
#pragma unroll
    for (int i = 0; i < 16; ++i) { p[i] = fexp2(p[i] - m_l); ps += p[i]; }
    ps += __shfl_xor(ps, 16);
    ps += __shfl_xor(ps, 32);
    l_l += ps;

    bf16x8 pa0, pa1;
#pragma unroll
    for (int j = 0; j < 4; ++j) {
      unsigned u0, u1, v0, v1;
      __builtin_memcpy(&u0, &p[2 * j], 4);
      __builtin_memcpy(&u1, &p[2 * j + 1], 4);
      __builtin_memcpy(&v0, &p[8 + 2 * j], 4);
      __builtin_memcpy(&v1, &p[8 + 2 * j + 1], 4);
      ((unsigned*)&pa0)[j] = (u0 >> 16) | (u1 & 0xFFFF0000u);
      ((unsigned*)&pa1)[j] = (v0 >> 16) | (v1 & 0xFFFF0000u);
    }
    __builtin_amdgcn_s_setprio(1);
#pragma unroll
    for (int ch = 0; ch < 4; ++ch) {
      int d = ch * 16 + lq;
      const char* vrow = (const char*)vt + d * 128;
      int swz = lq & 7;
      bf16x8 bv0 = *(const bf16x8*)(vrow + (((2 * lg + 0) ^ swz) << 4));
      bf16x8 bv1 = *(const bf16x8*)(vrow + (((2 * lg + 1) ^ swz) << 4));
      acc[ch] = __builtin_amdgcn_mfma_f32_16x16x32_bf16(pa0, bv0, acc[ch], 0, 0, 0);
      acc[ch] = __builtin_amdgcn_mfma_f32_16x16x32_bf16(pa1, bv1, acc[ch], 0, 0, 0);
    }
    __builtin_amdgcn_s_setprio(0);
  };

  for (int step = 0; step < 12; ++step) step_body(step * 64, false);
  step_body(12 * 64, true);

  if (lg == 0) axl[wid][lq] = l_l;
  f32x4 lv = *(const f32x4*)&axl[wid][lg * 4];
  int b = bh / NUM_HEADS, h = bh - b * NUM_HEADS;
#pragma unroll
  for (int r = 0; r < 4; ++r) {
    int qi = qbase + wid * 16 + lg * 4 + r;
    if (qi < NTOK) {
      float inv = 1.f / lv[r];
#pragma unroll
      for (int ch = 0; ch < 4; ++ch) {
        int d = ch * 16 + lq;
        float o = acc[ch][r] * inv + bf2f(qh[((size_t)bh * NTOK + qi) * HEAD_DIM + d]);
        Afin[((size_t)b * NTOK + qi) * DMODEL + h * HEAD_DIM + d] = f2bf(o);
      }
    }
  }
}

// ------------------------------------------------------------------- launcher
extern "C" void kernel_launch(void* const* d_in, const int* in_sizes, int n_in,
                              void* d_out, int out_size, void* d_ws, size_t ws_size,
                              hipStream_t stream)
{
  (void)in_sizes; (void)n_in; (void)out_size; (void)ws_size;
  const float* x   = (const float*)d_in[0];
  const float* pqw = (const float*)d_in[1];
  const float* pkw = (const float*)d_in[2];
  const float* pvw = (const float*)d_in[3];
  const float* gq  = (const float*)d_in[4];
  const float* bq_ = (const float*)d_in[5];
  const float* gk  = (const float*)d_in[6];
  const float* bk_ = (const float*)d_in[7];
  const float* gv  = (const float*)d_in[8];
  const float* bv_ = (const float*)d_in[9];
  const float* wq  = (const float*)d_in[10];
  const float* bqp = (const float*)d_in[11];
  const float* wk  = (const float*)d_in[12];
  const float* bkp = (const float*)d_in[13];
  const float* wv  = (const float*)d_in[14];
  const float* bvp = (const float*)d_in[15];
  const float* wp  = (const float*)d_in[16];
  const float* bpp = (const float*)d_in[17];
  const float* rph = (const float*)d_in[18];
  const float* rpw = (const float*)d_in[19];

  char* ws = (char*)d_ws;
  size_t off = 0;
  auto alloc = [&](size_t bytes) -> void* {
    void* p = ws + off; off += (bytes + 255) & ~(size_t)255; return p;
  };
  const size_t MROWS = (size_t)BATCH * NTOK;   // 12560
  short* Pq  = (short*)alloc(MROWS * DMODEL * 2);
  short* Pk  = (short*)alloc(MROWS * DMODEL * 2);
  short* Pv  = (short*)alloc(MROWS * DMODEL * 2);
  short* WqT = (short*)alloc((size_t)DMODEL * DMODEL * 2);
  short* WkT = (short*)alloc((size_t)DMODEL * DMODEL * 2);
  short* WvT = (short*)alloc((size_t)DMODEL * DMODEL * 2);
  short* WpT = (short*)alloc((size_t)DMODEL * DMODEL * 2);
  short* qhd = (short*)alloc(MROWS * DMODEL * 2 + 4096);
  short* khd = (short*)alloc(MROWS * DMODEL * 2 + 4096);
  short* vtg = (short*)alloc(MROWS * DMODEL * 2 + 8192);   // transposed V
  short* qaug = (short*)alloc((size_t)BHCNT * NTOK * 128 * 2 + 8192);
  short* kaug = (short*)alloc((size_t)BHCNT * NTOK * 128 * 2 + 8192);
  short* Afin = (short*)alloc(MROWS * DMODEL * 2);

  pool_ln_kernel<<<dim3(16 * 197), 192, 0, stream>>>(
      x, pqw, pkw, pvw, gq, bq_, gk, bk_, gv, bv_, Pq, Pk, Pv);
  trans_kernel<<<dim3(24, 24, 4), dim3(32, 8), 0, stream>>>(
      wq, wk, wv, wp, WqT, WkT, WvT, WpT);
  gemm_qkv_kernel<<<dim3(1782), 256, 0, stream>>>(
      Pq, WqT, bqp, qhd, Pk, WkT, bkp, khd, WvT, Pv, bvp, vtg);
  qaug_kernel<<<dim3(9420), 256, 0, stream>>>(qhd, qaug);
  kaug_kernel<<<dim3(9420), 256, 0, stream>>>(khd, kaug);
  relbias_kernel<<<dim3(28, BHCNT, 2), 256, 0, stream>>>(qhd, rph, rpw, qaug);
  flash7_kernel<<<dim3(2496), 256, 0, stream>>>(qaug, qhd, kaug, vtg, Afin);
  gemm_proj_kernel<<<dim3(594), 256, 0, stream>>>(Afin, WpT, bpp, (float*)d_out);
}

// Round 12
// 355.508 us; speedup vs baseline: 1.5382x; 1.0596x over previous
//
#include <hip/hip_runtime.h>
#include <stdint.h>

#define NUM_HEADS 12
#define HEAD_DIM  64
#define HWDIM     56
#define PHDIM     28
#define NTOK      785     // 28*28+1
#define NIN       3137    // 56*56+1
#define BATCH     16
#define DMODEL    768
#define BHCNT     192     // BATCH*NUM_HEADS
#define LOG2E     1.44269504f

typedef __attribute__((ext_vector_type(8))) short bf16x8;
typedef __attribute__((ext_vector_type(4))) short s16x4;
typedef __attribute__((ext_vector_type(4))) float f32x4;

static __device__ __forceinline__ float bf2f(short s) {
  unsigned u = ((unsigned)(unsigned short)s) << 16;
  float f; __builtin_memcpy(&f, &u, 4); return f;
}
static __device__ __forceinline__ short f2bf(float f) {
  unsigned u; __builtin_memcpy(&u, &f, 4);
  unsigned r = u + 0x7FFFu + ((u >> 16) & 1u);
  return (short)(r >> 16);
}
static __device__ __forceinline__ float fexp2(float x) {
#if defined(__has_builtin)
#if __has_builtin(__builtin_amdgcn_exp2f)
  return __builtin_amdgcn_exp2f(x);
#else
  return exp2f(x);
#endif
#else
  return exp2f(x);
#endif
}

// bijective XCD chunking (m204)
static __device__ __forceinline__ int xcd_chunk(int orig, int nwg) {
  int xcd = orig & 7;
  int within = orig >> 3;
  int q = nwg >> 3, r = nwg & 7;
  int base = (xcd < r) ? xcd * (q + 1) : r * (q + 1) + (xcd - r) * q;
  return base + within;
}

#if defined(__has_builtin)
#if __has_builtin(__builtin_amdgcn_global_load_lds)
#define HAVE_GLLDS 1
#endif
#endif

static __device__ __forceinline__ void gl_lds16(const short* g, short* l) {
#ifdef HAVE_GLLDS
  __builtin_amdgcn_global_load_lds(
      (const __attribute__((address_space(1))) void*)g,
      (__attribute__((address_space(3))) void*)l, 16, 0, 0);
#else
  int lane = threadIdx.x & 63;
  *(bf16x8*)(l + lane * 8) = *(const bf16x8*)g;
#endif
}

// ---------------------------------------------------------------- pool + LN
__global__ __launch_bounds__(192) void pool_ln_kernel(
    const float* __restrict__ x,
    const float* __restrict__ wq9, const float* __restrict__ wk9, const float* __restrict__ wv9,
    const float* __restrict__ gq, const float* __restrict__ bq,
    const float* __restrict__ gk, const float* __restrict__ bk,
    const float* __restrict__ gv, const float* __restrict__ bv,
    short* __restrict__ Pq, short* __restrict__ Pk, short* __restrict__ Pv)
{
  __shared__ __align__(16) float wt_s[3][9][64];   // [conv][tap][c]
  int tid = threadIdx.x;
  int blk = xcd_chunk(blockIdx.x, 16 * 197);   // L2 locality: neighbors same XCD
  int b = blk / 197;
  int n0 = (blk - b * 197) * 4;

  for (int idx = tid; idx < 3 * 576; idx += 192) {
    int conv = idx / 576, rem = idx - conv * 576;
    int c = rem / 9, tap = rem - c * 9;
    const float* wsrc = (conv == 0) ? wq9 : (conv == 1) ? wk9 : wv9;
    wt_s[conv][tap][c] = wsrc[c * 9 + tap];
  }
  __syncthreads();

  int ch0 = tid * 4;
  int c4 = ch0 & 63;
  f32x4 g_q = *(const f32x4*)&gq[c4], b_q = *(const f32x4*)&bq[c4];
  f32x4 g_k = *(const f32x4*)&gk[c4], b_k = *(const f32x4*)&bk[c4];
  f32x4 g_v = *(const f32x4*)&gv[c4], b_v = *(const f32x4*)&bv[c4];

  for (int tt = 0; tt < 4; ++tt) {
    int n = n0 + tt;
    if (n >= NTOK) break;
    f32x4 aq = (f32x4){0.f, 0.f, 0.f, 0.f}, ak = aq, av = aq;
    if (n == 0) {
      f32x4 x4 = *(const f32x4*)&x[((size_t)b * NIN) * DMODEL + ch0];
      aq = ak = av = x4;
    } else {
      int s = n - 1;
      int i = s / PHDIM, j = s - i * PHDIM;
#pragma unroll
      for (int di = 0; di < 3; ++di) {
        int ii = 2 * i - 1 + di;
        if (ii < 0 || ii >= HWDIM) continue;
#pragma unroll
        for (int dj = 0; dj < 3; ++dj) {
          int jj = 2 * j - 1 + dj;
          if (jj < 0 || jj >= HWDIM) continue;
          f32x4 x4 = *(const f32x4*)&x[((size_t)b * NIN + 1 + ii * HWDIM + jj) * DMODEL + ch0];
          int tap = di * 3 + dj;
          f32x4 w0 = *(const f32x4*)&wt_s[0][tap][c4];
          f32x4 w1 = *(const f32x4*)&wt_s[1][tap][c4];
          f32x4 w2 = *(const f32x4*)&wt_s[2][tap][c4];
          aq += w0 * x4; ak += w1 * x4; av += w2 * x4;
        }
      }
    }
    size_t obase = ((size_t)b * NTOK + n) * DMODEL + ch0;
    {
      float sm = aq[0] + aq[1] + aq[2] + aq[3];
#pragma unroll
      for (int m = 1; m < 16; m <<= 1) sm += __shfl_xor(sm, m);
      float mn = sm * (1.f / 64.f);
      f32x4 d = aq - mn;
      float vs = d[0]*d[0] + d[1]*d[1] + d[2]*d[2] + d[3]*d[3];
#pragma unroll
      for (int m = 1; m < 16; m <<= 1) vs += __shfl_xor(vs, m);
      float rs = rsqrtf(vs * (1.f / 64.f) + 1e-5f);
      s16x4 o;
#pragma unroll
      for (int e = 0; e < 4; ++e) o[e] = f2bf(d[e] * rs * g_q[e] + b_q[e]);
      *(s16x4*)&Pq[obase] = o;
    }
    {
      float sm = ak[0] + ak[1] + ak[2] + ak[3];
#pragma unroll
      for (int m = 1; m < 16; m <<= 1) sm += __shfl_xor(sm, m);
      float mn = sm * (1.f / 64.f);
      f32x4 d = ak - mn;
      float vs = d[0]*d[0] + d[1]*d[1] + d[2]*d[2] + d[3]*d[3];
#pragma unroll
      for (int m = 1; m < 16; m <<= 1) vs += __shfl_xor(vs, m);
      float rs = rsqrtf(vs * (1.f / 64.f) + 1e-5f);
      s16x4 o;
#pragma unroll
      for (int e = 0; e < 4; ++e) o[e] = f2bf(d[e] * rs * g_k[e] + b_k[e]);
      *(s16x4*)&Pk[obase] = o;
    }
    {
      float sm = av[0] + av[1] + av[2] + av[3];
#pragma unroll
      for (int m = 1; m < 16; m <<= 1) sm += __shfl_xor(sm, m);
      float mn = sm * (1.f / 64.f);
      f32x4 d = av - mn;
      float vs = d[0]*d[0] + d[1]*d[1] + d[2]*d[2] + d[3]*d[3];
#pragma unroll
      for (int m = 1; m < 16; m <<= 1) vs += __shfl_xor(vs, m);
      float rs = rsqrtf(vs * (1.f / 64.f) + 1e-5f);
      s16x4 o;
#pragma unroll
      for (int e = 0; e < 4; ++e) o[e] = f2bf(d[e] * rs * g_v[e] + b_v[e]);
      *(s16x4*)&Pv[obase] = o;
    }
  }
}

// ------------------------------------------------- weight transpose fp32->bf16
__global__ __launch_bounds__(256) void trans_kernel(
    const float* __restrict__ s0, const float* __restrict__ s1,
    const float* __restrict__ s2, const float* __restrict__ s3,
    short* __restrict__ d0, short* __restrict__ d1,
    short* __restrict__ d2, short* __restrict__ d3)
{
  __shared__ float tile[32][33];
  int z = blockIdx.z;
  const float* s = (z == 0) ? s0 : (z == 1) ? s1 : (z == 2) ? s2 : s3;
  short* d = (z == 0) ? d0 : (z == 1) ? d1 : (z == 2) ? d2 : d3;
  int k0 = blockIdx.x * 32, n0 = blockIdx.y * 32;
  int tx = threadIdx.x, ty = threadIdx.y;   // 32 x 8
#pragma unroll
  for (int jj = 0; jj < 4; ++jj)
    tile[ty + jj * 8][tx] = s[(size_t)(k0 + ty + jj * 8) * DMODEL + n0 + tx];
  __syncthreads();
#pragma unroll
  for (int jj = 0; jj < 4; ++jj)
    d[(size_t)(n0 + ty + jj * 8) * DMODEL + k0 + tx] = f2bf(tile[tx][ty + jj * 8]);
}

// ------------------------------------------------------------- GEMM core
// 128x128, BK=32, 2-phase dbuf, single barrier per K-step.
// mode0: fp32 row-major (bias[col]); mode1: bf16 (B,12,785,64);
// mode2: bf16 transposed (bias[row]);
// mode3: q-path -> outp=qhd (B,12,785,64) AND outp2=qaug (scaled, upper zeroed)
// mode4: k-path -> outp2=kaug (value + one-hot upper)
static __device__ __forceinline__ void gemm_core(
    short* As, short* Bs,
    const short* __restrict__ A, const short* __restrict__ Bt,
    const float* __restrict__ bias, void* __restrict__ outp, void* __restrict__ outp2,
    int rowbase, int colbase, int M, int Nn, int mode)
{
  const int K = DMODEL;
  int tid = threadIdx.x;
  int wid = tid >> 6, lane = tid & 63;
  int lg = lane >> 4, lq = lane & 15;
  int wm = wid >> 1, wn = wid & 1;

  f32x4 acc[4][4];
#pragma unroll
  for (int i = 0; i < 4; ++i)
#pragma unroll
    for (int j = 0; j < 4; ++j) acc[i][j] = (f32x4){0.f, 0.f, 0.f, 0.f};

  int srow = tid >> 2;
  int scol = (tid & 3) * 8;
  int ar0 = min(rowbase + srow, M - 1);
  int ar1 = min(rowbase + 64 + srow, M - 1);
  int br0 = min(colbase + srow, Nn - 1);
  int br1 = min(colbase + 64 + srow, Nn - 1);
  const short* Ag0 = A + (size_t)ar0 * K + scol;
  const short* Ag1 = A + (size_t)ar1 * K + scol;
  const short* Bg0 = Bt + (size_t)br0 * K + scol;
  const short* Bg1 = Bt + (size_t)br1 * K + scol;

  auto stage = [&](int kt, int buf) __attribute__((always_inline)) {
    short* Ab = As + buf * 4096;
    short* Bb = Bs + buf * 4096;
    gl_lds16(Ag0 + kt, Ab + wid * 512);
    gl_lds16(Ag1 + kt, Ab + 2048 + wid * 512);
    gl_lds16(Bg0 + kt, Bb + wid * 512);
    gl_lds16(Bg1 + kt, Bb + 2048 + wid * 512);
  };

  stage(0, 0);
  __syncthreads();
  int cur = 0;
  for (int kt = 0; kt < K; kt += 32) {
    if (kt + 32 < K) stage(kt + 32, cur ^ 1);
    const short* Ac = As + cur * 4096;
    const short* Bc = Bs + cur * 4096;
    bf16x8 aFrag[4], bFrag[4];
#pragma unroll
    for (int mi = 0; mi < 4; ++mi)
      aFrag[mi] = *(const bf16x8*)&Ac[(wm * 64 + mi * 16 + lq) * 32 + lg * 8];
#pragma unroll
    for (int ni = 0; ni < 4; ++ni)
      bFrag[ni] = *(const bf16x8*)&Bc[(wn * 64 + ni * 16 + lq) * 32 + lg * 8];
    __builtin_amdgcn_s_setprio(1);
#pragma unroll
    for (int mi = 0; mi < 4; ++mi)
#pragma unroll
      for (int ni = 0; ni < 4; ++ni)
        acc[mi][ni] = __builtin_amdgcn_mfma_f32_16x16x32_bf16(aFrag[mi], bFrag[ni], acc[mi][ni], 0, 0, 0);
    __builtin_amdgcn_s_setprio(0);
    __syncthreads();
    cur ^= 1;
  }

  if (mode >= 3) {
    const float s2 = 0.125f * LOG2E;
    int myhead = (colbase >> 6) + wn;
#pragma unroll
    for (int mi = 0; mi < 4; ++mi) {
      int rowq = rowbase + wm * 64 + mi * 16 + lg * 4;
#pragma unroll
      for (int r = 0; r < 4; ++r) {
        int row = rowq + r;
        if (row < M) {
          int bb = row / NTOK, nn = row - bb * NTOK;
          size_t abase = ((size_t)(bb * NUM_HEADS + myhead) * NTOK + nn) * 128;
#pragma unroll
          for (int ni = 0; ni < 4; ++ni) {
            int col = colbase + wn * 64 + ni * 16 + lq;
            int c = col & 63;
            float v = acc[mi][ni][r] + bias[col];
            if (mode == 3) {
              ((short*)outp)[(((size_t)(bb * NUM_HEADS + myhead) * NTOK + nn) << 6) + c] = f2bf(v);
              ((short*)outp2)[abase + c] = f2bf(v * s2);
            } else {
              ((short*)outp2)[abase + c] = f2bf(v);
            }
          }
        }
      }
    }
    // aug upper half [64:128): zeros (q) / one-hot (k); one row per lane
    int rz = rowbase + wm * 64 + lane;
    if (rz < M) {
      int bb = rz / NTOK, nn = rz - bb * NTOK;
      short* dst = (short*)outp2 + ((size_t)(bb * NUM_HEADS + myhead) * NTOK + nn) * 128 + 64;
      if (mode == 3) {
        bf16x8 z = {0, 0, 0, 0, 0, 0, 0, 0};
#pragma unroll
        for (int zc = 0; zc < 8; ++zc) *(bf16x8*)(dst + zc * 8) = z;
      } else {
        int ki = -100, kj = -100;
        if (nn >= 1) { int km1 = nn - 1; ki = km1 / PHDIM; kj = km1 - ki * PHDIM; }
#pragma unroll
        for (int zc = 0; zc < 8; ++zc) {
          bf16x8 o = {0, 0, 0, 0, 0, 0, 0, 0};
#pragma unroll
          for (int e = 0; e < 8; ++e) {
            int d = 64 + zc * 8 + e;
            if (d == 64 + ki || d == 92 + kj) o[e] = (short)0x3F80;
          }
          *(bf16x8*)(dst + zc * 8) = o;
        }
      }
    }
    return;
  }

#pragma unroll
  for (int mi = 0; mi < 4; ++mi) {
    int rowq = rowbase + wm * 64 + mi * 16 + lg * 4;
#pragma unroll
    for (int r = 0; r < 4; ++r) {
      int row = rowq + r;
      if (row < M) {
        if (mode == 2) {
          float bb = bias[row];
#pragma unroll
          for (int ni = 0; ni < 4; ++ni) {
            int col = colbase + wn * 64 + ni * 16 + lq;
            if (col < Nn) {
              int b = col / NTOK, n = col - b * NTOK;
              float v = acc[mi][ni][r] + bb;
              ((short*)outp)[((size_t)b * DMODEL + row) * NTOK + n] = f2bf(v);
            }
          }
        } else {
          int bb = row / NTOK;
          int nn = row - bb * NTOK;
#pragma unroll
          for (int ni = 0; ni < 4; ++ni) {
            int col = colbase + wn * 64 + ni * 16 + lq;
            float v = acc[mi][ni][r] + bias[col];
            if (mode == 0) {
              ((float*)outp)[(size_t)row * DMODEL + col] = v;
            } else {
              ((short*)outp)[(((size_t)(bb * NUM_HEADS + (col >> 6)) * NTOK + nn) << 6) + (col & 63)] = f2bf(v);
            }
          }
        }
      }
    }
  }
}

__global__ __launch_bounds__(256) void gemm_qkv_kernel(
    const short* __restrict__ Pq, const short* __restrict__ WqT,
    const float* __restrict__ bq, short* __restrict__ qhd, short* __restrict__ qaug,
    const short* __restrict__ Pk, const short* __restrict__ WkT,
    const float* __restrict__ bk, short* __restrict__ kaug,
    const short* __restrict__ WvT, const short* __restrict__ Pv,
    const float* __restrict__ bv, short* __restrict__ vtg)
{
  __shared__ short As[2 * 4096];
  __shared__ short Bs[2 * 4096];
  const int NWG = 1782;
  int lid = xcd_chunk(blockIdx.x, NWG);
  if (lid < 1188) {
    int which = lid / 594;
    int sub = lid - which * 594;
    int rowbase = (sub / 6) * 128;
    int colbase = (sub % 6) * 128;
    if (which == 0)
      gemm_core(As, Bs, Pq, WqT, bq, (void*)qhd, (void*)qaug,
                rowbase, colbase, BATCH * NTOK, DMODEL, 3);
    else
      gemm_core(As, Bs, Pk, WkT, bk, nullptr, (void*)kaug,
                rowbase, colbase, BATCH * NTOK, DMODEL, 4);
  } else {
    int sub = lid - 1188;
    int rowbase = (sub % 6) * 128;
    int colbase = (sub / 6) * 128;
    gemm_core(As, Bs, WvT, Pv, bv, (void*)vtg, nullptr,
              rowbase, colbase, DMODEL, BATCH * NTOK, 2);
  }
}

__global__ __launch_bounds__(256) void gemm_proj_kernel(
    const short* __restrict__ Afin, const short* __restrict__ WpT,
    const float* __restrict__ bp, float* __restrict__ outp)
{
  __shared__ short As[2 * 4096];
  __shared__ short Bs[2 * 4096];
  const int NWG = 594;
  int lid = xcd_chunk(blockIdx.x, NWG);
  int rowbase = (lid / 6) * 128;
  int colbase = (lid % 6) * 128;
  gemm_core(As, Bs, Afin, WpT, bp, (void*)outp, nullptr,
            rowbase, colbase, BATCH * NTOK, DMODEL, 0);
}

// -------------------------------------------------------- rel-pos bias tables
// writes log2e-scaled bias rows directly into qaug dims [64:120)
__global__ __launch_bounds__(256) void relbias_kernel(
    const short* __restrict__ qh, const float* __restrict__ rph,
    const float* __restrict__ rpw, short* __restrict__ qaug)
{
  int line = blockIdx.x;   // i (mode0) or j (mode1)
  int bh = blockIdx.y;
  int mode = blockIdx.z;
  __shared__ __align__(16) float qt_s[28 * 68];
  __shared__ __align__(16) float rt_s[28 * 68];
  int tid = threadIdx.x;
  const float* rp = (mode == 0) ? rph : rpw;
  for (int idx = tid; idx < 28 * 64; idx += 256) {
    int rr = idx >> 6, c = idx & 63;
    int qi = (mode == 0) ? (1 + line * PHDIM + rr) : (1 + rr * PHDIM + line);
    qt_s[rr * 68 + c] = bf2f(qh[((size_t)bh * NTOK + qi) * HEAD_DIM + c]);
    rt_s[rr * 68 + c] = rp[(line - rr + 27) * HEAD_DIM + c];
  }
  __syncthreads();
  for (int o = tid; o < 784; o += 256) {
    int kk = o / PHDIM, rr = o - kk * PHDIM;
    const f32x4* qa = (const f32x4*)&qt_s[rr * 68];
    const f32x4* ra = (const f32x4*)&rt_s[kk * 68];
    f32x4 a4 = (f32x4){0.f, 0.f, 0.f, 0.f};
#pragma unroll
    for (int i = 0; i < 16; ++i) a4 += qa[i] * ra[i];
    float s = (a4[0] + a4[1] + a4[2] + a4[3]) * LOG2E;
    int qi = (mode == 0) ? (1 + line * PHDIM + rr) : (1 + rr * PHDIM + line);
    int dim = (mode == 0) ? (64 + kk) : (92 + kk);
    qaug[((size_t)bh * NTOK + qi) * 128 + dim] = f2bf(s);
  }
}

// ------------------------------------------------------------ flash attention
// augmented QK (bias inside MFMA); sigma-permuted K rows; lane-local P.
__global__ __launch_bounds__(256) void flash7_kernel(
    const short* __restrict__ qaug, const short* __restrict__ qh,
    const short* __restrict__ kaug, const short* __restrict__ vtg,
    short* __restrict__ Afin)
{
  int id = blockIdx.x;
  int slot = id >> 3;
  int bh = (id & 7) * 24 + slot / 13;   // all 13 q-tiles of a bh on one XCD
  int qt = slot - (slot / 13) * 13;
  int qbase = qt * 64;
  int tid = threadIdx.x, wid = tid >> 6, lane = tid & 63;
  int lg = lane >> 4, lq = lane & 15;

  __shared__ __align__(16) short ks[64 * 128];   // sigma-permuted K_aug rows (16 slots, swz rr&15)
  __shared__ __align__(16) short vt[64 * 64];    // V^T[d][key] (8 slots, swz d&7)
  __shared__ __align__(16) float axl[4][16];

  int qi0 = qbase + wid * 16 + lq;
  int qiq = min(qi0, NTOK - 1);
  const short* qrow = qaug + ((size_t)bh * NTOK + qiq) * 128;
  bf16x8 bq[4];
#pragma unroll
  for (int c = 0; c < 4; ++c) bq[c] = *(const bf16x8*)(qrow + c * 32 + lg * 8);

  float m_l = -3e30f, l_l = 0.f;
  f32x4 acc[4];
#pragma unroll
  for (int ch = 0; ch < 4; ++ch) acc[ch] = (f32x4){0.f, 0.f, 0.f, 0.f};

  const short* kbase = kaug + (size_t)bh * NTOK * 128;
  const short* vbase = vtg + (size_t)bh * (size_t)HEAD_DIM * NTOK;

  int koffK[4], kslot[4];
#pragma unroll
  for (int m = 0; m < 4; ++m) {
    int c = m * 256 + tid;
    int rr = c >> 4, j = c & 15;
    koffK[m] = ((rr & 15) >> 2) * 16 + (rr >> 4) * 4 + (rr & 3);
    kslot[m] = (j ^ (rr & 15)) << 3;
  }
  int c0 = tid, c1 = 256 + tid;
  int vr0 = c0 >> 3, vj0 = c0 & 7;
  int vr1 = c1 >> 3, vj1 = c1 & 7;
  const short* vsrc0 = vbase + (size_t)vr0 * NTOK + ((vj0 ^ (vr0 & 7)) << 3);
  const short* vsrc1 = vbase + (size_t)vr1 * NTOK + ((vj1 ^ (vr1 & 7)) << 3);

  auto step_body = [&](int kvb, bool last) __attribute__((always_inline)) {
    __syncthreads();
#pragma unroll
    for (int m = 0; m < 4; ++m)
      gl_lds16(kbase + (size_t)min(kvb + koffK[m], NTOK - 1) * 128 + kslot[m],
               ks + m * 2048 + wid * 512);
    gl_lds16(vsrc0 + kvb, vt + wid * 512);
    gl_lds16(vsrc1 + kvb, vt + 2048 + wid * 512);
    __syncthreads();

    float p[16];
#pragma unroll
    for (int kt = 0; kt < 4; ++kt) {
      int kl = kt * 16 + lq;
      const char* kp = (const char*)ks + kl * 256;
      int swz = kl & 15;
      f32x4 s = (f32x4){0.f, 0.f, 0.f, 0.f};
      __builtin_amdgcn_s_setprio(1);
#pragma unroll
      for (int c = 0; c < 4; ++c) {
        bf16x8 aK = *(const bf16x8*)(kp + (((c * 4 + lg) ^ swz) << 4));
        s = __builtin_amdgcn_mfma_f32_16x16x32_bf16(aK, bq[c], s, 0, 0, 0);
      }
      __builtin_amdgcn_s_setprio(0);
#pragma unroll
      for (int r = 0; r < 4; ++r) {
        int i = kt * 4 + r;
        float v = s[r];
        if (last) {
          int key = kvb + 16 * lg + i;
          if (key >= NTOK) v = -3e30f;
        }
        p[i] = v;
      }
    }

    float pm = p[0];
#pragma unroll
    for (int i = 1; i < 16; ++i) pm = fmaxf(pm, p[i]);
    pm = fmaxf(pm, __shfl_xor(pm, 16));
    pm = fmaxf(pm, __shfl_xor(pm, 32));
    if (!__all(pm - m_l <= 11.5f)) {
      float mnew = fmaxf(m_l, pm);
      float alpha = fexp2(m_l - mnew);
      m_l = mnew;
      l_l *= alpha;
      if (lg == 0) axl[wid][lq] = alpha;
      f32x4 av = *(const f32x4*)&axl[wid][lg * 4];
#pragma unroll
      for (int ch = 0; ch < 4; ++ch)
#pragma unroll
        for (int r = 0; r < 4; ++r) acc[ch][r] *= av[r];
    }
    float ps = 0.f;
#pragma unroll
    for (int i = 0; i < 16; ++i) { p[i] = fexp2(p[i] - m_l); ps += p[i]; }
    ps += __shfl_xor(ps, 16);
    ps += __shfl_xor(ps, 32);
    l_l += ps;

    bf16x8 pa0, pa1;
#pragma unroll
    for (int j = 0; j < 4; ++j) {
      unsigned u0, u1, v0, v1;
      __builtin_memcpy(&u0, &p[2 * j], 4);
      __builtin_memcpy(&u1, &p[2 * j + 1], 4);
      __builtin_memcpy(&v0, &p[8 + 2 * j], 4);
      __builtin_memcpy(&v1, &p[8 + 2 * j + 1], 4);
      ((unsigned*)&pa0)[j] = (u0 >> 16) | (u1 & 0xFFFF0000u);
      ((unsigned*)&pa1)[j] = (v0 >> 16) | (v1 & 0xFFFF0000u);
    }
    __builtin_amdgcn_s_setprio(1);
#pragma unroll
    for (int ch = 0; ch < 4; ++ch) {
      int d = ch * 16 + lq;
      const char* vrow = (const char*)vt + d * 128;
      int swz = lq & 7;
      bf16x8 bv0 = *(const bf16x8*)(vrow + (((2 * lg + 0) ^ swz) << 4));
      bf16x8 bv1 = *(const bf16x8*)(vrow + (((2 * lg + 1) ^ swz) << 4));
      acc[ch] = __builtin_amdgcn_mfma_f32_16x16x32_bf16(pa0, bv0, acc[ch], 0, 0, 0);
      acc[ch] = __builtin_amdgcn_mfma_f32_16x16x32_bf16(pa1, bv1, acc[ch], 0, 0, 0);
    }
    __builtin_amdgcn_s_setprio(0);
  };

  for (int step = 0; step < 12; ++step) step_body(step * 64, false);
  step_body(12 * 64, true);

  if (lg == 0) axl[wid][lq] = l_l;
  f32x4 lv = *(const f32x4*)&axl[wid][lg * 4];
  int b = bh / NUM_HEADS, h = bh - b * NUM_HEADS;
#pragma unroll
  for (int r = 0; r < 4; ++r) {
    int qi = qbase + wid * 16 + lg * 4 + r;
    if (qi < NTOK) {
      float inv = 1.f / lv[r];
#pragma unroll
      for (int ch = 0; ch < 4; ++ch) {
        int d = ch * 16 + lq;
        float o = acc[ch][r] * inv + bf2f(qh[((size_t)bh * NTOK + qi) * HEAD_DIM + d]);
        Afin[((size_t)b * NTOK + qi) * DMODEL + h * HEAD_DIM + d] = f2bf(o);
      }
    }
  }
}

// ------------------------------------------------------------------- launcher
extern "C" void kernel_launch(void* const* d_in, const int* in_sizes, int n_in,
                              void* d_out, int out_size, void* d_ws, size_t ws_size,
                              hipStream_t stream)
{
  (void)in_sizes; (void)n_in; (void)out_size; (void)ws_size;
  const float* x   = (const float*)d_in[0];
  const float* pqw = (const float*)d_in[1];
  const float* pkw = (const float*)d_in[2];
  const float* pvw = (const float*)d_in[3];
  const float* gq  = (const float*)d_in[4];
  const float* bq_ = (const float*)d_in[5];
  const float* gk  = (const float*)d_in[6];
  const float* bk_ = (const float*)d_in[7];
  const float* gv  = (const float*)d_in[8];
  const float* bv_ = (const float*)d_in[9];
  const float* wq  = (const float*)d_in[10];
  const float* bqp = (const float*)d_in[11];
  const float* wk  = (const float*)d_in[12];
  const float* bkp = (const float*)d_in[13];
  const float* wv  = (const float*)d_in[14];
  const float* bvp = (const float*)d_in[15];
  const float* wp  = (const float*)d_in[16];
  const float* bpp = (const float*)d_in[17];
  const float* rph = (const float*)d_in[18];
  const float* rpw = (const float*)d_in[19];

  char* ws = (char*)d_ws;
  size_t off = 0;
  auto alloc = [&](size_t bytes) -> void* {
    void* p = ws + off; off += (bytes + 255) & ~(size_t)255; return p;
  };
  const size_t MROWS = (size_t)BATCH * NTOK;   // 12560
  short* Pq  = (short*)alloc(MROWS * DMODEL * 2);
  short* Pk  = (short*)alloc(MROWS * DMODEL * 2);
  short* Pv  = (short*)alloc(MROWS * DMODEL * 2);
  short* WqT = (short*)alloc((size_t)DMODEL * DMODEL * 2);
  short* WkT = (short*)alloc((size_t)DMODEL * DMODEL * 2);
  short* WvT = (short*)alloc((size_t)DMODEL * DMODEL * 2);
  short* WpT = (short*)alloc((size_t)DMODEL * DMODEL * 2);
  short* qhd = (short*)alloc(MROWS * DMODEL * 2 + 4096);
  short* vtg = (short*)alloc(MROWS * DMODEL * 2 + 8192);   // transposed V
  short* qaug = (short*)alloc((size_t)BHCNT * NTOK * 128 * 2 + 8192);
  short* kaug = (short*)alloc((size_t)BHCNT * NTOK * 128 * 2 + 8192);
  short* Afin = (short*)alloc(MROWS * DMODEL * 2);

  pool_ln_kernel<<<dim3(16 * 197), 192, 0, stream>>>(
      x, pqw, pkw, pvw, gq, bq_, gk, bk_, gv, bv_, Pq, Pk, Pv);
  trans_kernel<<<dim3(24, 24, 4), dim3(32, 8), 0, stream>>>(
      wq, wk, wv, wp, WqT, WkT, WvT, WpT);
  gemm_qkv_kernel<<<dim3(1782), 256, 0, stream>>>(
      Pq, WqT, bqp, qhd, qaug, Pk, WkT, bkp, kaug, WvT, Pv, bvp, vtg);
  relbias_kernel<<<dim3(28, BHCNT, 2), 256, 0, stream>>>(qhd, rph, rpw, qaug);
  flash7_kernel<<<dim3(2496), 256, 0, stream>>>(qaug, qhd, kaug, vtg, Afin);
  gemm_proj_kernel<<<dim3(594), 256, 0, stream>>>(Afin, WpT, bpp, (float*)d_out);
}